// Round 3
// baseline (520.717 us; speedup 1.0000x reference)
//
#include <hip/hip_runtime.h>
#include <hip/hip_bf16.h>
#include <float.h>

// Problem constants
#define NB 128
#define DD 64
#define NTOT (NB*32*32)     // 131072
#define KC 512

// d_out element offsets (fp32, concatenated in return order)
#define OFF_LOSS  0
#define OFF_QUANT 1
#define OFF_PERP  8388609
#define OFF_OH    8388610

// scratch inside d_out's oh region (overwritten by vq_onehot afterwards)
#define EHI_F  8388612                 // bf16 hi table, 512x64 bf16 = 16384 floats
#define ELO_F  (EHI_F + 16384)
#define DIST_F (ELO_F + 16384)         // per-row approx min dist, NTOT floats

// ws word layout: [0] loss accum; [1..512] counts (int); [1024..1535] enorm; [2048..] idx
#define WS_COUNTS 1
#define WS_ENORM  1024
#define WS_IDX    2048

#define FLAG_BIT  (1 << 16)
#define TAU       1.5e-3f

typedef __attribute__((ext_vector_type(8))) short short8;
typedef __attribute__((ext_vector_type(4))) float f32x4;

__device__ inline unsigned short f2bf(float f) {
    unsigned u = __builtin_bit_cast(unsigned, f);
    unsigned r = (u + 0x7fffu + ((u >> 16) & 1u)) >> 16;   // RNE
    return (unsigned short)r;
}
__device__ inline float bf2f(unsigned short h) {
    return __builtin_bit_cast(float, ((unsigned)h) << 16);
}

// prep: zero loss+counts; enorm (fp64-accurate) -> ws; codebook -> bf16 hi/lo tables in out-scratch
__global__ __launch_bounds__(256)
void vq_prep(const float* __restrict__ cb, float* __restrict__ ws,
             float* __restrict__ out) {
    int t = blockIdx.x * 256 + threadIdx.x;   // 0..511
    if (t == 0) ws[0] = 0.0f;
    ((int*)ws)[WS_COUNTS + t] = 0;
    short* ehi = (short*)(out + EHI_F);
    short* elo = (short*)(out + ELO_F);
    const float* row = cb + (t << 6);
    double s = 0.0;
#pragma unroll
    for (int j = 0; j < 8; ++j) {
        float4 a = *(const float4*)(row + j*8);
        float4 b = *(const float4*)(row + j*8 + 4);
        float v[8] = {a.x,a.y,a.z,a.w,b.x,b.y,b.z,b.w};
        short8 h8, l8;
#pragma unroll
        for (int e = 0; e < 8; ++e) {
            s += (double)v[e] * (double)v[e];
            unsigned short h = f2bf(v[e]);
            float hf = bf2f(h);
            unsigned short l = f2bf(v[e] - hf);
            h8[e] = (short)h; l8[e] = (short)l;
        }
        *(short8*)(ehi + (t << 6) + j*8) = h8;
        *(short8*)(elo + (t << 6) + j*8) = l8;
    }
    ws[WS_ENORM + t] = (float)s;
}

// Pass 1: bf16-split MFMA distance + lane-local argmin (swapped operands:
// A = codebook tile (16 codes x 32 d), B = X tile (32 d x 16 rows)).
// WG = 256 thr = 4 waves; WG owns 128 x-rows; wave w owns rows [w*32, w*32+32).
// C/D layout (m89-verified): col = lane&15 = x-row, row = k-code = (lane>>4)*4 + reg.
__global__ __launch_bounds__(256)
void vq_argmin(const float* __restrict__ x, const float* __restrict__ ws_enorm,
               const float* __restrict__ out_scratch,
               int* __restrict__ idx_out, int* __restrict__ counts,
               float* __restrict__ loss_acc, float* __restrict__ dist_out) {
    // X tiled for MFMA B-frags: [xt][ks][g][c][8d] bf16
    __shared__ __align__(16) short Xh[8][2][4][16][8];
    __shared__ __align__(16) short Xl[8][2][4][16][8];
    __shared__ float en_s[512];
    __shared__ float xn_s[128];

    int t = threadIdx.x;
    int n0 = blockIdx.x * 128;
    int b  = n0 >> 10;
    int sp0 = n0 & 1023;
    const float* xbase = x + ((size_t)b << 16) + sp0;

    // ---- stage X: coalesced float4 over rows, scatter bf16 hi/lo into tiled LDS ----
#pragma unroll
    for (int i = 0; i < 8; ++i) {
        int e4 = i * 256 + t;              // 0..2047 float4 units (64 d x 32 r4)
        int d  = e4 >> 5;
        int r4 = (e4 & 31) << 2;
        float4 v4 = *(const float4*)(xbase + (size_t)d * 1024 + r4);
        float v[4] = {v4.x, v4.y, v4.z, v4.w};
        int ks = d >> 5, g = (d >> 3) & 3, dj = d & 7;
#pragma unroll
        for (int j = 0; j < 4; ++j) {
            int r = r4 + j;
            unsigned short h = f2bf(v[j]);
            float hf = bf2f(h);
            unsigned short l = f2bf(v[j] - hf);
            Xh[r >> 4][ks][g][r & 15][dj] = (short)h;
            Xl[r >> 4][ks][g][r & 15][dj] = (short)l;
        }
    }
    // enorm -> LDS
    en_s[t]       = ws_enorm[t];
    en_s[t + 256] = ws_enorm[t + 256];
    __syncthreads();

    // per-row ||x||^2 (reconstructed: err ~1e-4, affects loss only, not argmin)
    if (t < 128) {
        float s = 0.0f;
        int xt = t >> 4, c = t & 15;
#pragma unroll
        for (int ks = 0; ks < 2; ++ks)
#pragma unroll
            for (int g = 0; g < 4; ++g) {
                short8 h8 = *(const short8*)&Xh[xt][ks][g][c][0];
                short8 l8 = *(const short8*)&Xl[xt][ks][g][c][0];
#pragma unroll
                for (int e = 0; e < 8; ++e) {
                    float xv = bf2f((unsigned short)h8[e]) + bf2f((unsigned short)l8[e]);
                    s = fmaf(xv, xv, s);
                }
            }
        xn_s[t] = s;
    }
    __syncthreads();

    int w = t >> 6, lane = t & 63;
    int c = lane & 15, g = lane >> 4;

    // B-frags: loop-invariant over k! [xt_local][ks]
    short8 bh[2][2], bl[2][2];
#pragma unroll
    for (int xl_ = 0; xl_ < 2; ++xl_) {
        int xt = w * 2 + xl_;
#pragma unroll
        for (int ks = 0; ks < 2; ++ks) {
            bh[xl_][ks] = *(const short8*)&Xh[xt][ks][g][c][0];
            bl[xl_][ks] = *(const short8*)&Xl[xt][ks][g][c][0];
        }
    }

    const short* pAh = (const short*)(out_scratch + EHI_F) + (c << 6) + (g << 3);
    const short* pAl = (const short*)(out_scratch + ELO_F) + (c << 6) + (g << 3);

    float v1[2] = {FLT_MAX, FLT_MAX}, v2[2] = {FLT_MAX, FLT_MAX};
    int   i1[2] = {0, 0},            i2[2] = {0, 0};

#pragma unroll 2
    for (int kt = 0; kt < 32; ++kt) {
        // A-frags for this 16-code tile (each lane: code kt*16+c, d-slice g*8)
        short8 ah0 = *(const short8*)(pAh + (kt << 10));
        short8 ah1 = *(const short8*)(pAh + (kt << 10) + 32);
        short8 al0 = *(const short8*)(pAl + (kt << 10));
        short8 al1 = *(const short8*)(pAl + (kt << 10) + 32);
        float4 en4 = *(const float4*)&en_s[(kt << 4) + (g << 2)];
#pragma unroll
        for (int xl_ = 0; xl_ < 2; ++xl_) {
            f32x4 acc = {0.f, 0.f, 0.f, 0.f};
            acc = __builtin_amdgcn_mfma_f32_16x16x32_bf16(ah0, bh[xl_][0], acc, 0, 0, 0);
            acc = __builtin_amdgcn_mfma_f32_16x16x32_bf16(ah1, bh[xl_][1], acc, 0, 0, 0);
            acc = __builtin_amdgcn_mfma_f32_16x16x32_bf16(al0, bh[xl_][0], acc, 0, 0, 0);
            acc = __builtin_amdgcn_mfma_f32_16x16x32_bf16(al1, bh[xl_][1], acc, 0, 0, 0);
            acc = __builtin_amdgcn_mfma_f32_16x16x32_bf16(ah0, bl[xl_][0], acc, 0, 0, 0);
            acc = __builtin_amdgcn_mfma_f32_16x16x32_bf16(ah1, bl[xl_][1], acc, 0, 0, 0);
            float en_[4] = {en4.x, en4.y, en4.z, en4.w};
#pragma unroll
            for (int r = 0; r < 4; ++r) {
                float dd = fmaf(-2.0f, acc[r], en_[r]);   // ||e||^2 - 2 x.e
                int k = (kt << 4) + (g << 2) + r;
                bool lt1 = dd < v1[xl_];
                bool lt2 = dd < v2[xl_];
                v2[xl_] = lt1 ? v1[xl_] : (lt2 ? dd : v2[xl_]);
                i2[xl_] = lt1 ? i1[xl_] : (lt2 ? k  : i2[xl_]);
                v1[xl_] = lt1 ? dd : v1[xl_];
                i1[xl_] = lt1 ? k  : i1[xl_];
            }
        }
    }

    // cross-lane: lanes {c, c+16, c+32, c+48} hold disjoint k-subsets of row c
    float dmin[2];
#pragma unroll
    for (int xl_ = 0; xl_ < 2; ++xl_) {
        float V1 = v1[xl_], V2 = v2[xl_]; int I1 = i1[xl_], I2 = i2[xl_];
#pragma unroll
        for (int off = 16; off <= 32; off <<= 1) {
            float o1 = __shfl_xor(V1, off); int oi1 = __shfl_xor(I1, off);
            float o2 = __shfl_xor(V2, off); int oi2 = __shfl_xor(I2, off);
            if (o1 < V1 || (o1 == V1 && oi1 < I1)) {
                V2 = V1; I2 = I1; V1 = o1; I1 = oi1;
            } else if (o1 < V2 || (o1 == V2 && oi1 < I2)) { V2 = o1; I2 = oi1; }
            if (o2 < V2 || (o2 == V2 && oi2 < I2)) { V2 = o2; I2 = oi2; }
        }
        v1[xl_] = V1; i1[xl_] = I1; v2[xl_] = V2;
        dmin[xl_] = 0.f;
        if (g == 0) {
            int xt = w * 2 + xl_;
            int n  = n0 + xt * 16 + c;
            int flag = (V2 - V1 < TAU) ? FLAG_BIT : 0;
            idx_out[n] = I1 | flag;
            float dm = xn_s[xt * 16 + c] + V1;
            dist_out[n] = dm;
            atomicAdd(&counts[I1], 1);
            dmin[xl_] = dm;
        }
    }
    // loss partial: g==0 lanes (0..15) hold 2 rows each
    float contrib = dmin[0] + dmin[1];
#pragma unroll
    for (int off = 1; off <= 8; off <<= 1) contrib += __shfl_xor(contrib, off);
    if (lane == 0) atomicAdd(loss_acc, contrib);
}

// Pass 2: exact fp64 full-scan for flagged rows; fix idx/counts/loss.
__global__ __launch_bounds__(256)
void vq_recheck(const float* __restrict__ x, const float* __restrict__ cb,
                int* __restrict__ idx_arr, int* __restrict__ counts,
                float* __restrict__ loss_acc, const float* __restrict__ dist_arr) {
    int wid  = blockIdx.x * 4 + (threadIdx.x >> 6);   // 2048 waves
    int lane = threadIdx.x & 63;
    int n0 = wid << 6;
    int iv = idx_arr[n0 + lane];
    bool fl = (iv & FLAG_BIT) != 0;
    unsigned long long m = __ballot(fl);
    int my_old = iv & 511;
    while (m) {
        int r = __ffsll((long long)m) - 1; m &= m - 1;
        int n = n0 + r;
        int oldi = __shfl(my_old, r);
        int bb = n >> 10, sp = n & 1023;
        float xd = x[((size_t)bb << 16) + ((size_t)lane << 10) + sp];  // x[b][lane][sp]
        double bestd = 1e300; int besti = 0x7fffffff;
#pragma unroll 2
        for (int kk = 0; kk < 8; ++kk) {
            int k = (lane << 3) + kk;
            const float* er = cb + ((size_t)k << 6);
            double s = 0.0;
            for (int d = 0; d < 64; ++d) {
                float xv = __shfl(xd, d);
                double df = (double)xv - (double)er[d];
                s = fma(df, df, s);
            }
            if (s < bestd || (s == bestd && k < besti)) { bestd = s; besti = k; }
        }
#pragma unroll
        for (int off = 32; off; off >>= 1) {
            double od = __shfl_xor(bestd, off);
            int    oi = __shfl_xor(besti, off);
            if (od < bestd || (od == bestd && oi < besti)) { bestd = od; besti = oi; }
        }
        if (lane == 0) {
            if (besti != oldi) {
                atomicSub(&counts[oldi], 1);
                atomicAdd(&counts[besti], 1);
                idx_arr[n] = besti;
                atomicAdd(loss_acc, (float)bestd - dist_arr[n]);
            } else {
                idx_arr[n] = oldi;   // strip flag
            }
        }
    }
}

// quantized_out[b][d][h][w] = codebook[idx[n]][d]
__global__ __launch_bounds__(256)
void vq_quant(const float* __restrict__ cb, const int* __restrict__ idx,
              float* __restrict__ qout) {
    int n = blockIdx.x * 256 + threadIdx.x;
    int b = n >> 10, sp = n & 1023;
    int k = idx[n];
    const float4* row = (const float4*)(cb + ((size_t)k << 6));
    float* obase = qout + (((size_t)b << 6) << 10) + sp;
#pragma unroll
    for (int d4 = 0; d4 < 16; ++d4) {
        float4 v = row[d4];
        obase[(size_t)(4*d4 + 0) * 1024] = v.x;
        obase[(size_t)(4*d4 + 1) * 1024] = v.y;
        obase[(size_t)(4*d4 + 2) * 1024] = v.z;
        obase[(size_t)(4*d4 + 3) * 1024] = v.w;
    }
}

// oh[b][k][sp] = (idx[b*1024+sp] == k); writes all 268 MB (incl. the scratch region)
__global__ __launch_bounds__(256)
void vq_onehot(const int* __restrict__ idx, float* __restrict__ oh) {
    int tid = blockIdx.x * 256 + threadIdx.x;
    int e0 = tid << 2;
    int sp = e0 & 1023;
    int bk = e0 >> 10;
    int k  = bk & 511;
    int b  = bk >> 9;
    int4 iv = *(const int4*)(idx + (b << 10) + sp);
    float2 lo = { iv.x == k ? 1.0f : 0.0f, iv.y == k ? 1.0f : 0.0f };
    float2 hi = { iv.z == k ? 1.0f : 0.0f, iv.w == k ? 1.0f : 0.0f };
    float* p = oh + e0;
    *(float2*)p = lo;
    *(float2*)(p + 2) = hi;
}

__global__ __launch_bounds__(512)
void vq_final(const float* __restrict__ ws, float* __restrict__ out) {
    __shared__ float sh[512];
    int t = threadIdx.x;
    const int* counts = (const int*)ws + WS_COUNTS;
    float p = (float)counts[t] * (1.0f / (float)NTOT);
    sh[t] = p * logf(p + 1e-10f);
    __syncthreads();
    for (int s = 256; s > 0; s >>= 1) {
        if (t < s) sh[t] += sh[t + s];
        __syncthreads();
    }
    if (t == 0) {
        out[OFF_PERP] = expf(-sh[0]);
        out[OFF_LOSS] = 0.25f * ws[0] / ((float)NTOT * 64.0f);
    }
}

extern "C" void kernel_launch(void* const* d_in, const int* in_sizes, int n_in,
                              void* d_out, int out_size, void* d_ws, size_t ws_size,
                              hipStream_t stream) {
    const float* x  = (const float*)d_in[0];
    const float* cb = (const float*)d_in[1];
    float* out = (float*)d_out;
    float* ws  = (float*)d_ws;

    float* loss_acc = ws;
    int*   counts   = (int*)ws + WS_COUNTS;
    float* enorm    = ws + WS_ENORM;
    int*   idx      = (int*)ws + WS_IDX;
    float* qout     = out + OFF_QUANT;
    float* oh       = out + OFF_OH;
    float* dist     = out + DIST_F;

    vq_prep   <<<2,        256, 0, stream>>>(cb, ws, out);
    vq_argmin <<<NTOT/128, 256, 0, stream>>>(x, enorm, out, idx, counts, loss_acc, dist);
    vq_recheck<<<512,      256, 0, stream>>>(x, cb, idx, counts, loss_acc, dist);
    vq_quant  <<<NTOT/256, 256, 0, stream>>>(cb, idx, qout);
    vq_onehot <<<(67108864/4)/256, 256, 0, stream>>>(idx, oh);
    vq_final  <<<1,        512, 0, stream>>>(ws, out);
}

// Round 4
// 452.542 us; speedup vs baseline: 1.1506x; 1.1506x over previous
//
#include <hip/hip_runtime.h>
#include <hip/hip_bf16.h>
#include <float.h>

// Problem: B=128, D=64, H=W=32, K=512. N = 131072 rows.
#define NTOT 131072

// d_out element offsets (fp32, concatenated in return order)
#define OFF_LOSS  0
#define OFF_QUANT 1
#define OFF_PERP  8388609
#define OFF_OH    8388610

#define FLAG_BIT (1 << 16)
#define TAU      1.5e-3f
#define MAGIC    0x5EEDF00D
#define WSTRIDE  516          // per-WG ints in ws: 512 hist + loss + flag + pad (256*516*4 = 528 KB)

typedef __attribute__((ext_vector_type(8))) short short8;
typedef __attribute__((ext_vector_type(4))) short short4v;
typedef __attribute__((ext_vector_type(4))) float f32x4;

__device__ inline unsigned short f2bf(float f) {
    unsigned u = __builtin_bit_cast(unsigned, f);
    unsigned r = (u + 0x7fffu + ((u >> 16) & 1u)) >> 16;   // RNE
    return (unsigned short)r;
}
__device__ inline float bf2f(unsigned short h) {
    return __builtin_bit_cast(float, ((unsigned)h) << 16);
}

// ONE persistent kernel. Grid 256 x 1024 (1 WG/CU, LDS-bound).
// WG wg owns rows n = wg*512 .. +512  (b = wg>>1, sp = (wg&1)*512 .. +512).
// Wave w owns 32 rows (2 MFMA x-tiles of 16). No grid barrier: the only
// cross-WG data (counts/loss -> perplexity) flows via ws + release/acquire
// flags; WG0 spins only AFTER all its own output writes (deadlock-free).
__global__ __launch_bounds__(1024)
void vq_fused(const float* __restrict__ x, const float* __restrict__ cb,
              int* __restrict__ wsi, float* __restrict__ out) {
    // 136 KiB LDS total (<=160 KiB/CU)
    __shared__ short Ehi[512 * 64];   // bf16 hi, XOR-swizzled 16B chunks
    __shared__ short Elo[512 * 64];   // bf16 lo
    __shared__ float en_s[512];
    __shared__ float dist_s[512];
    __shared__ int   idx_s[512];
    __shared__ int   hist_s[512];

    const int t = threadIdx.x, wg = blockIdx.x;
    const int w = t >> 6, lane = t & 63;
    const int c = lane & 15, g = lane >> 4;
    const int b0 = wg >> 1;
    const int sphalf = (wg & 1) << 9;
    float* qout = out + OFF_QUANT;
    float* oh   = out + OFF_OH;

    if (t < 512) hist_s[t] = 0;

    // ---- stage codebook -> LDS bf16 hi/lo, swizzle: 16B chunk' = chunk ^ (k&7) ----
    const float4* cb4 = (const float4*)cb;
#pragma unroll
    for (int i = 0; i < 8; ++i) {
        int e4 = i * 1024 + t;                 // 8192 float4 = full codebook, coalesced
        float4 v = cb4[e4];
        int k = e4 >> 4, q = e4 & 15;
        int base = (k << 6) + ((((q >> 1) ^ (k & 7)) << 3) + ((q & 1) << 2));
        float vv[4] = {v.x, v.y, v.z, v.w};
        short4v h4, l4;
#pragma unroll
        for (int e = 0; e < 4; ++e) {
            unsigned short h = f2bf(vv[e]);
            h4[e] = (short)h;
            l4[e] = (short)f2bf(vv[e] - bf2f(h));
        }
        *(short4v*)&Ehi[base] = h4;
        *(short4v*)&Elo[base] = l4;
    }
    // ---- ||e||^2 fp32 (from global, L2-hot) ----
    if (t < 512) {
        const float4* r4 = cb4 + (t << 4);
        float s = 0.f;
#pragma unroll
        for (int j = 0; j < 16; ++j) {
            float4 vv = r4[j];
            s = fmaf(vv.x, vv.x, s); s = fmaf(vv.y, vv.y, s);
            s = fmaf(vv.z, vv.z, s); s = fmaf(vv.w, vv.w, s);
        }
        en_s[t] = s;
    }

    // ---- X B-frags + xnorm, registers only (coalesced-ish 64B segments) ----
    short8 bh[2][2], bl[2][2];
    float xn2[2] = {0.f, 0.f};
    const float* xb = x + (((size_t)b0) << 16) + sphalf + (w << 5) + c;
#pragma unroll
    for (int xt = 0; xt < 2; ++xt) {
#pragma unroll
        for (int ks = 0; ks < 2; ++ks) {
            short8 h8, l8;
#pragma unroll
            for (int e = 0; e < 8; ++e) {
                float xv = xb[(xt << 4) + ((size_t)((ks << 5) + (g << 3) + e) << 10)];
                unsigned short hh = f2bf(xv);
                h8[e] = (short)hh;
                l8[e] = (short)f2bf(xv - bf2f(hh));
                xn2[xt] = fmaf(xv, xv, xn2[xt]);
            }
            bh[xt][ks] = h8; bl[xt][ks] = l8;
        }
    }
    float xnorm[2];
#pragma unroll
    for (int xt = 0; xt < 2; ++xt) {
        float v = xn2[xt];
        v += __shfl_xor(v, 16);
        v += __shfl_xor(v, 32);
        xnorm[xt] = v;
    }
    __syncthreads();

    // ---- MFMA argmin over 32 k-tiles (A from swizzled LDS) ----
    float v1[2] = {FLT_MAX, FLT_MAX}, v2[2] = {FLT_MAX, FLT_MAX};
    int   i1[2] = {0, 0},            i2v[2] = {0, 0};
    const int sw = c & 7;
    const short* ph = &Ehi[c << 6];
    const short* pl = &Elo[c << 6];
#pragma unroll 2
    for (int kt = 0; kt < 32; ++kt) {
        const short* rh = ph + (kt << 10);
        const short* rl = pl + (kt << 10);
        short8 ah0 = *(const short8*)(rh + ((g ^ sw) << 3));
        short8 ah1 = *(const short8*)(rh + (((g + 4) ^ sw) << 3));
        short8 al0 = *(const short8*)(rl + ((g ^ sw) << 3));
        short8 al1 = *(const short8*)(rl + (((g + 4) ^ sw) << 3));
        float4 en4 = *(const float4*)&en_s[(kt << 4) + (g << 2)];
        float en_[4] = {en4.x, en4.y, en4.z, en4.w};
#pragma unroll
        for (int xt = 0; xt < 2; ++xt) {
            f32x4 acc = {0.f, 0.f, 0.f, 0.f};
            acc = __builtin_amdgcn_mfma_f32_16x16x32_bf16(ah0, bh[xt][0], acc, 0, 0, 0);
            acc = __builtin_amdgcn_mfma_f32_16x16x32_bf16(ah1, bh[xt][1], acc, 0, 0, 0);
            acc = __builtin_amdgcn_mfma_f32_16x16x32_bf16(al0, bh[xt][0], acc, 0, 0, 0);
            acc = __builtin_amdgcn_mfma_f32_16x16x32_bf16(al1, bh[xt][1], acc, 0, 0, 0);
            acc = __builtin_amdgcn_mfma_f32_16x16x32_bf16(ah0, bl[xt][0], acc, 0, 0, 0);
            acc = __builtin_amdgcn_mfma_f32_16x16x32_bf16(ah1, bl[xt][1], acc, 0, 0, 0);
#pragma unroll
            for (int r = 0; r < 4; ++r) {
                float dd = fmaf(-2.0f, acc[r], en_[r]);
                int k = (kt << 4) + (g << 2) + r;
                bool lt1 = dd < v1[xt];
                bool lt2 = dd < v2[xt];
                v2[xt] = lt1 ? v1[xt] : (lt2 ? dd : v2[xt]);
                i2v[xt] = lt1 ? i1[xt] : (lt2 ? k : i2v[xt]);
                v1[xt] = lt1 ? dd : v1[xt];
                i1[xt] = lt1 ? k : i1[xt];
            }
        }
    }

    // ---- cross-lane merge (lanes c, c+16, c+32, c+48 hold disjoint k-classes) ----
#pragma unroll
    for (int xt = 0; xt < 2; ++xt) {
        float V1 = v1[xt], V2 = v2[xt]; int I1 = i1[xt], I2 = i2v[xt];
#pragma unroll
        for (int off = 16; off <= 32; off <<= 1) {
            float o1 = __shfl_xor(V1, off); int oi1 = __shfl_xor(I1, off);
            float o2 = __shfl_xor(V2, off); int oi2 = __shfl_xor(I2, off);
            if (o1 < V1 || (o1 == V1 && oi1 < I1)) {
                V2 = V1; I2 = I1; V1 = o1; I1 = oi1;
            } else if (o1 < V2 || (o1 == V2 && oi1 < I2)) { V2 = o1; I2 = oi1; }
            if (o2 < V2 || (o2 == V2 && oi2 < I2)) { V2 = o2; I2 = oi2; }
        }
        if (g == 0) {
            int r = (w << 5) + (xt << 4) + c;
            idx_s[r]  = I1 | ((V2 - V1 < TAU) ? FLAG_BIT : 0);
            dist_s[r] = xnorm[xt] + V1;
        }
    }
    __syncthreads();

    // ---- fp64 recheck of near-ties (wave-local, ~0.3% of rows) ----
    {
        int full = idx_s[(w << 5) + (lane & 31)];
        unsigned long long m = __ballot((lane < 32) && (full & FLAG_BIT));
        while (m) {
            int r = __ffsll((long long)m) - 1; m &= m - 1;
            int sp = sphalf + (w << 5) + r;
            float xd = x[(((size_t)b0) << 16) + (((size_t)lane) << 10) + sp];
            double bestd = 1e300; int besti = 0x7fffffff;
            for (int kk = 0; kk < 8; ++kk) {
                int k = (lane << 3) + kk;
                const float* er = cb + (((size_t)k) << 6);
                double s = 0.0;
                for (int d = 0; d < 64; ++d) {
                    float xv = __shfl(xd, d);
                    double df = (double)xv - (double)er[d];
                    s = fma(df, df, s);
                }
                if (s < bestd || (s == bestd && k < besti)) { bestd = s; besti = k; }
            }
#pragma unroll
            for (int off = 32; off; off >>= 1) {
                double od = __shfl_xor(bestd, off);
                int    oi = __shfl_xor(besti, off);
                if (od < bestd || (od == bestd && oi < besti)) { bestd = od; besti = oi; }
            }
            if (lane == 0) {
                idx_s[(w << 5) + r]  = besti;
                dist_s[(w << 5) + r] = (float)bestd;
            }
        }
    }
    __syncthreads();

    // ---- WG stats: strip flags, histogram, loss partial ----
    if (t < 512) {
        int k = idx_s[t] & 511;
        idx_s[t] = k;
        atomicAdd(&hist_s[k], 1);
        float v = dist_s[t];
#pragma unroll
        for (int off = 1; off < 64; off <<= 1) v += __shfl_xor(v, off);
        if (lane == 0) en_s[w] = v;           // en_s dead; reuse as scratch (w = 0..7)
    }
    __syncthreads();
    if (t < 512)
        __hip_atomic_store(&wsi[wg * WSTRIDE + t], hist_s[t],
                           __ATOMIC_RELAXED, __HIP_MEMORY_SCOPE_AGENT);
    if (t == 0) {
        float lsum = 0.f;
        for (int i = 0; i < 8; ++i) lsum += en_s[i];
        __hip_atomic_store(&wsi[wg * WSTRIDE + 512], __float_as_int(lsum),
                           __ATOMIC_RELAXED, __HIP_MEMORY_SCOPE_AGENT);
    }
    __syncthreads();
    if (t == 0)
        __hip_atomic_store(&wsi[wg * WSTRIDE + 513], MAGIC,
                           __ATOMIC_RELEASE, __HIP_MEMORY_SCOPE_AGENT);

    // ---- phase 2a: onehot slice (WG-local idx; 1 MB of float2 stores) ----
    {
        const int pr = lane & 15, kk = lane >> 4;
        int2 iv = *(const int2*)&idx_s[(w << 5) + (pr << 1)];
        float* ohb = oh + (((size_t)b0) << 19) + sphalf + (w << 5) + (pr << 1);
#pragma unroll 4
        for (int kb = 0; kb < 512; kb += 4) {
            int k = kb + kk;
            float2 o;
            o.x = (iv.x == k) ? 1.f : 0.f;
            o.y = (iv.y == k) ? 1.f : 0.f;
            *(float2*)(ohb + (((size_t)k) << 10)) = o;
        }
    }
    // ---- phase 2b: quantized (reconstruct hi+lo from LDS; err <= 2e-5) ----
    {
        const int sp_l = lane & 31, dg = lane >> 5;
        int k = idx_s[(w << 5) + sp_l];
        const short* phq = &Ehi[k << 6];
        const short* plq = &Elo[k << 6];
        const int swq = k & 7;
        float* qb = qout + (((size_t)b0) << 16) + sphalf + (w << 5) + sp_l;
#pragma unroll
        for (int dblk = 0; dblk < 4; ++dblk) {
            int chunk = (dg << 2) + dblk;
            short8 h8 = *(const short8*)(phq + ((chunk ^ swq) << 3));
            short8 l8 = *(const short8*)(plq + ((chunk ^ swq) << 3));
#pragma unroll
            for (int e = 0; e < 8; ++e) {
                float v = bf2f((unsigned short)h8[e]) + bf2f((unsigned short)l8[e]);
                qb[((size_t)((dg << 5) + (dblk << 3) + e)) << 10] = v;
            }
        }
    }

    // ---- WG0 only: gather stats, perplexity + loss (after own writes) ----
    if (wg == 0) {
        if (t < 256) {
            while (__hip_atomic_load(&wsi[t * WSTRIDE + 513],
                                     __ATOMIC_ACQUIRE, __HIP_MEMORY_SCOPE_AGENT) != MAGIC)
                __builtin_amdgcn_s_sleep(2);
        }
        __syncthreads();
        float plog = 0.f, lpart = 0.f;
        if (t < 512) {
            int s = 0;
            for (int wgi = 0; wgi < 256; ++wgi)
                s += __hip_atomic_load(&wsi[wgi * WSTRIDE + t],
                                       __ATOMIC_RELAXED, __HIP_MEMORY_SCOPE_AGENT);
            float p = (float)s * (1.f / (float)NTOT);
            plog = p * logf(p + 1e-10f);
        }
        if (t < 256)
            lpart = __int_as_float(__hip_atomic_load(&wsi[t * WSTRIDE + 512],
                                       __ATOMIC_RELAXED, __HIP_MEMORY_SCOPE_AGENT));
#pragma unroll
        for (int off = 1; off < 64; off <<= 1) {
            plog  += __shfl_xor(plog, off);
            lpart += __shfl_xor(lpart, off);
        }
        __syncthreads();
        if (lane == 0 && w < 8) en_s[w] = plog;
        if (lane == 0 && w < 4) dist_s[w] = lpart;
        __syncthreads();
        if (t == 0) {
            float ps = 0.f; for (int i = 0; i < 8; ++i) ps += en_s[i];
            float ls = 0.f; for (int i = 0; i < 4; ++i) ls += dist_s[i];
            out[OFF_PERP] = expf(-ps);
            out[OFF_LOSS] = 0.25f * ls / ((float)NTOT * 64.0f);
        }
    }
}

extern "C" void kernel_launch(void* const* d_in, const int* in_sizes, int n_in,
                              void* d_out, int out_size, void* d_ws, size_t ws_size,
                              hipStream_t stream) {
    const float* x  = (const float*)d_in[0];
    const float* cb = (const float*)d_in[1];
    vq_fused<<<256, 1024, 0, stream>>>(x, cb, (int*)d_ws, (float*)d_out);
}